// Round 6
// baseline (225.124 us; speedup 1.0000x reference)
//
#include <hip/hip_runtime.h>
#include <math.h>

// Problem constants
#define BATCH   16
#define CDIM    512
#define HWDIM   9216      // 96*96
#define NCLS    64
#define TILE    128
#define NTILES  72        // 9216/128
#define NCHUNK  16        // 512/32

// Output layout (floats): heatmap[16*9216], logits[16], loss[1], ip[16*64*9216]
#define LOGOFF  147456
#define LOSSOFF 147472
#define IPOFF   147473

// Workspace layout (floats)
#define WS_CC   0         // combined centers [128][512] fp32 (0..63 centers, 64..127 new)
#define WS_S    65536     // s[64]
#define WS_PH   65600     // per-block heat sums [1152]
#define WS_PC   66752     // per-block cluster sums [1152]
#define WS_AP   67904     // A-piece fragments: 16 chunks * 3p * 8mb * 64lane * 4 floats
#define WS_MIX  166208    // mix [64][512]

typedef __attribute__((ext_vector_type(8))) short bf16x8;
typedef __attribute__((ext_vector_type(4))) float f32x4;

__device__ __forceinline__ void split3(float v, float& h, float& m, float& l) {
  float hf = __uint_as_float(__float_as_uint(v) & 0xFFFF0000u);
  float r  = v - hf;                    // exact
  float mf = __uint_as_float(__float_as_uint(r) & 0xFFFF0000u);
  float r2 = r - mf;                    // exact
  float lf = __uint_as_float(__float_as_uint(r2) & 0xFFFF0000u);
  h = hf; m = mf; l = lf;
}

__device__ __forceinline__ unsigned packbf(float a, float b) {
  return (__float_as_uint(a) >> 16) | (__float_as_uint(b) & 0xFFFF0000u);
}

// ---------------------------------------------------------------------------
// prep1: a-normalized mix rows, centers copy, s[n]
// ---------------------------------------------------------------------------
__global__ __launch_bounds__(256) void prep1_kernel(
    const float* __restrict__ centers, const float* __restrict__ Aadj,
    const float* __restrict__ W_bc, const float* __restrict__ b_bc,
    float* __restrict__ ws) {
  __shared__ float a_n[NCLS];
  __shared__ float red[256];
  const int n = blockIdx.x;
  const int tid = threadIdx.x;

  if (tid < NCLS) a_n[tid] = Aadj[n * NCLS + tid] + (tid == n ? 1.0f : 0.0f);
  __syncthreads();
  if (tid == 0) {
    float ssum = 0.f;
    for (int w = 0; w < NCLS; ++w) ssum += a_n[w];
    red[0] = 1.0f / ssum;
  }
  __syncthreads();
  float inv = red[0];
  __syncthreads();
  if (tid < NCLS) a_n[tid] *= inv;
  __syncthreads();

  float p = 0.f;
  for (int c = tid; c < CDIM; c += 256) {
    float v = centers[n * CDIM + c];
    ws[WS_CC + n * CDIM + c] = v;
    float acc = 0.f;
    #pragma unroll 8
    for (int w = 0; w < NCLS; ++w) acc = fmaf(a_n[w], centers[w * CDIM + c], acc);
    ws[WS_MIX + n * CDIM + c] = 0.05f * v + 0.95f * acc;
    p = fmaf(W_bc[c], v, p);
  }
  red[tid] = p;
  __syncthreads();
  for (int st = 128; st > 0; st >>= 1) {
    if (tid < st) red[tid] += red[tid + st];
    __syncthreads();
  }
  if (tid == 0) ws[WS_S + n] = red[0] + b_bc[0];
}

// ---------------------------------------------------------------------------
// prep2: new_centers[n][o] = b_gcn[o] + sum_k W_gcn[o][k]*cat[k][n]
// ---------------------------------------------------------------------------
__global__ __launch_bounds__(256) void prep2_kernel(
    const float* __restrict__ W_gcn, const float* __restrict__ b_gcn,
    float* __restrict__ ws) {
  __shared__ float catT[128][65];
  const int tid = threadIdx.x;
  const int oo = tid >> 6, n = tid & 63;
  const int o = blockIdx.x * 4 + oo;
  const float* Wrow = W_gcn + (size_t)o * 1024;
  float acc = b_gcn[o];

  for (int k0 = 0; k0 < 1024; k0 += 128) {
    __syncthreads();
    const float* srcb = (k0 < 512) ? (ws + WS_CC + k0) : (ws + WS_MIX + (k0 - 512));
    #pragma unroll
    for (int i = 0; i < 32; ++i) {
      int idx = i * 256 + tid;
      int kk = idx & 127, n2 = idx >> 7;
      catT[kk][n2] = srcb[(size_t)n2 * CDIM + kk];
    }
    __syncthreads();
    #pragma unroll 16
    for (int kk = 0; kk < 128; ++kk)
      acc = fmaf(Wrow[k0 + kk], catT[kk][n], acc);
  }
  ws[WS_CC + (size_t)(NCLS + n) * CDIM + o] = acc;
}

// ---------------------------------------------------------------------------
// Pack: split CC into 3 bf16 pieces, fragment-linear per (chunk,p,mb,lane)
// ---------------------------------------------------------------------------
__global__ __launch_bounds__(256) void pack_kernel(float* __restrict__ ws) {
  const int gid = blockIdx.x * 256 + threadIdx.x;   // 8192 = 16c*8mb*64lane
  const int lane = gid & 63;
  const int mb = (gid >> 6) & 7;
  const int c = gid >> 9;
  const int row = mb * 16 + (lane & 15);
  const int kb = c * 32 + ((lane >> 4) & 3) * 8;
  const float* src = ws + WS_CC + (size_t)row * CDIM + kb;
  float e[8];
  *(float4*)&e[0] = *(const float4*)(src);
  *(float4*)&e[4] = *(const float4*)(src + 4);
  unsigned dh[4], dm[4], dl[4];
  #pragma unroll
  for (int d = 0; d < 4; ++d) {
    float h0, m0, l0, h1, m1, l1;
    split3(e[2 * d], h0, m0, l0);
    split3(e[2 * d + 1], h1, m1, l1);
    dh[d] = packbf(h0, h1); dm[d] = packbf(m0, m1); dl[d] = packbf(l0, l1);
  }
  const size_t base = WS_AP + (size_t)c * 6144 + (size_t)mb * 256 + (size_t)lane * 4;
  *(uint4*)(ws + base)        = make_uint4(dh[0], dh[1], dh[2], dh[3]);
  *(uint4*)(ws + base + 2048) = make_uint4(dm[0], dm[1], dm[2], dm[3]);
  *(uint4*)(ws + base + 4096) = make_uint4(dl[0], dl[1], dl[2], dl[3]);
}

// ---------------------------------------------------------------------------
// Main: MFMA split-bf16 dual GEMM. 2x2 wave decomposition (wave owns 64 cols
// x (32 ip rows + 32 nip rows)) -> halved LDS B-read traffic. B reg-staged
// with 1-chunk lead into double-buffered LDS, A fragments from L1/L2,
// one __syncthreads per chunk (R3-proven skeleton).
// ---------------------------------------------------------------------------
__global__ __launch_bounds__(256, 3) void main_kernel(
    const float* __restrict__ x, const float* __restrict__ gumbel,
    float* __restrict__ ws, float* __restrict__ out) {
  __shared__ char ldsmem[49152];          // 2 x 24576 B-piece buffers
  __shared__ float s_sh[NCLS];
  char* buf0 = ldsmem;
  char* buf1 = ldsmem + 24576;

  const int tid = threadIdx.x;
  const int w = tid >> 6, l = tid & 63;
  const int wn = w & 1, wm = w >> 1;
  const int q = l >> 4, c15 = l & 15;
  const int tile = blockIdx.x, b = blockIdx.y;
  const int hw0 = tile * TILE;

  if (tid < NCLS) s_sh[tid] = ws[WS_S + tid];

  const float* xb = x + (size_t)b * CDIM * HWDIM;
  const float* pB = xb + (size_t)(w * 8) * HWDIM + hw0 + l;   // k = c*32 + w*8 + j
  const char* ap = (const char*)(ws + WS_AP);
  const int la16 = l * 16;
  const int aipb = 2 * wm;     // ip A regions aipb, aipb+1; nip: 4+aipb, 5+aipb

  f32x4 cip[2][4], cnp[2][4];
  #pragma unroll
  for (int mb = 0; mb < 2; ++mb)
    #pragma unroll
    for (int nbl = 0; nbl < 4; ++nbl) {
      cip[mb][nbl] = (f32x4){0.f, 0.f, 0.f, 0.f};
      cnp[mb][nbl] = (f32x4){0.f, 0.f, 0.f, 0.f};
    }

  float br[16];

#define LOADB(c_) do {                                                        \
    const size_t koff = (size_t)(c_) * 32 * HWDIM;                            \
    _Pragma("unroll")                                                         \
    for (int j = 0; j < 8; ++j) {                                             \
      br[j]     = pB[koff + (size_t)j * HWDIM];                               \
      br[8 + j] = pB[koff + (size_t)j * HWDIM + 64];                          \
    }                                                                         \
  } while (0)

#define WRITE_B(WB) do {                                                      \
    _Pragma("unroll")                                                         \
    for (int hh = 0; hh < 2; ++hh) {                                          \
      unsigned dh[4], dm[4], dl[4];                                           \
      _Pragma("unroll")                                                       \
      for (int d = 0; d < 4; ++d) {                                           \
        float h0, m0, l0, h1, m1, l1;                                         \
        split3(br[hh * 8 + 2 * d], h0, m0, l0);                               \
        split3(br[hh * 8 + 2 * d + 1], h1, m1, l1);                           \
        dh[d] = packbf(h0, h1); dm[d] = packbf(m0, m1); dl[d] = packbf(l0, l1);\
      }                                                                       \
      char* basep = (WB) + ((((l >> 4) + hh * 4) * 64) + (w << 4) + (l & 15)) * 16; \
      *(uint4*)(basep)         = make_uint4(dh[0], dh[1], dh[2], dh[3]);      \
      *(uint4*)(basep + 8192)  = make_uint4(dm[0], dm[1], dm[2], dm[3]);      \
      *(uint4*)(basep + 16384) = make_uint4(dl[0], dl[1], dl[2], dl[3]);      \
    }                                                                         \
  } while (0)

#define PHASE(c_, RB) do {                                                    \
    const char* asrc = ap + (size_t)(c_) * 24576;                             \
    bf16x8 aH0 = *(const bf16x8*)(asrc + (aipb + 0) * 1024 + la16);           \
    bf16x8 aM0 = *(const bf16x8*)(asrc + 8192 + (aipb + 0) * 1024 + la16);    \
    bf16x8 aL0 = *(const bf16x8*)(asrc + 16384 + (aipb + 0) * 1024 + la16);   \
    bf16x8 aH1 = *(const bf16x8*)(asrc + (aipb + 1) * 1024 + la16);           \
    bf16x8 aM1 = *(const bf16x8*)(asrc + 8192 + (aipb + 1) * 1024 + la16);    \
    bf16x8 aL1 = *(const bf16x8*)(asrc + 16384 + (aipb + 1) * 1024 + la16);   \
    bf16x8 nH0 = *(const bf16x8*)(asrc + (4 + aipb) * 1024 + la16);           \
    bf16x8 nM0 = *(const bf16x8*)(asrc + 8192 + (4 + aipb) * 1024 + la16);    \
    bf16x8 nH1 = *(const bf16x8*)(asrc + (5 + aipb) * 1024 + la16);           \
    bf16x8 nM1 = *(const bf16x8*)(asrc + 8192 + (5 + aipb) * 1024 + la16);    \
    _Pragma("unroll")                                                         \
    for (int nbl = 0; nbl < 4; ++nbl) {                                       \
      const int nb = wn * 4 + nbl;                                            \
      bf16x8 bH = *(const bf16x8*)((RB) + nb * 1024 + la16);                  \
      bf16x8 bM = *(const bf16x8*)((RB) + 8192 + nb * 1024 + la16);           \
      bf16x8 bL = *(const bf16x8*)((RB) + 16384 + nb * 1024 + la16);          \
      cip[0][nbl] = __builtin_amdgcn_mfma_f32_16x16x32_bf16(aH0, bH, cip[0][nbl], 0, 0, 0); \
      cip[0][nbl] = __builtin_amdgcn_mfma_f32_16x16x32_bf16(aH0, bM, cip[0][nbl], 0, 0, 0); \
      cip[0][nbl] = __builtin_amdgcn_mfma_f32_16x16x32_bf16(aM0, bH, cip[0][nbl], 0, 0, 0); \
      cip[0][nbl] = __builtin_amdgcn_mfma_f32_16x16x32_bf16(aH0, bL, cip[0][nbl], 0, 0, 0); \
      cip[0][nbl] = __builtin_amdgcn_mfma_f32_16x16x32_bf16(aM0, bM, cip[0][nbl], 0, 0, 0); \
      cip[0][nbl] = __builtin_amdgcn_mfma_f32_16x16x32_bf16(aL0, bH, cip[0][nbl], 0, 0, 0); \
      cip[1][nbl] = __builtin_amdgcn_mfma_f32_16x16x32_bf16(aH1, bH, cip[1][nbl], 0, 0, 0); \
      cip[1][nbl] = __builtin_amdgcn_mfma_f32_16x16x32_bf16(aH1, bM, cip[1][nbl], 0, 0, 0); \
      cip[1][nbl] = __builtin_amdgcn_mfma_f32_16x16x32_bf16(aM1, bH, cip[1][nbl], 0, 0, 0); \
      cip[1][nbl] = __builtin_amdgcn_mfma_f32_16x16x32_bf16(aH1, bL, cip[1][nbl], 0, 0, 0); \
      cip[1][nbl] = __builtin_amdgcn_mfma_f32_16x16x32_bf16(aM1, bM, cip[1][nbl], 0, 0, 0); \
      cip[1][nbl] = __builtin_amdgcn_mfma_f32_16x16x32_bf16(aL1, bH, cip[1][nbl], 0, 0, 0); \
      cnp[0][nbl] = __builtin_amdgcn_mfma_f32_16x16x32_bf16(nH0, bH, cnp[0][nbl], 0, 0, 0); \
      cnp[0][nbl] = __builtin_amdgcn_mfma_f32_16x16x32_bf16(nH0, bM, cnp[0][nbl], 0, 0, 0); \
      cnp[0][nbl] = __builtin_amdgcn_mfma_f32_16x16x32_bf16(nM0, bH, cnp[0][nbl], 0, 0, 0); \
      cnp[1][nbl] = __builtin_amdgcn_mfma_f32_16x16x32_bf16(nH1, bH, cnp[1][nbl], 0, 0, 0); \
      cnp[1][nbl] = __builtin_amdgcn_mfma_f32_16x16x32_bf16(nH1, bM, cnp[1][nbl], 0, 0, 0); \
      cnp[1][nbl] = __builtin_amdgcn_mfma_f32_16x16x32_bf16(nM1, bH, cnp[1][nbl], 0, 0, 0); \
    }                                                                         \
  } while (0)

  // prologue: chunk 0 staged into buf0
  LOADB(0);
  WRITE_B(buf0);
  __syncthreads();

  #pragma unroll 1
  for (int c = 0; c < NCHUNK; c += 2) {
    LOADB(c + 1);                       // 1-chunk lead, consumed by WRITE_B below
    PHASE(c, buf0);
    WRITE_B(buf1);
    __syncthreads();
    if (c + 2 < NCHUNK) LOADB(c + 2);
    PHASE(c + 1, buf1);
    if (c + 2 < NCHUNK) WRITE_B(buf0);
    __syncthreads();
  }

  // ---------------- epilogue ----------------
  float* pvv  = (float*)ldsmem;           // [2][128]
  int*   pvi  = (int*)(ldsmem + 1024);
  float* pnm  = (float*)(ldsmem + 2048);
  float* pns  = (float*)(ldsmem + 3072);
  float* m2   = (float*)(ldsmem + 4096);  // [128]
  float* hbuf = (float*)(ldsmem + 4608);
  float* cbuf = (float*)(ldsmem + 5120);

  const size_t bn = (size_t)b * NCLS;
  float* ipo = out + IPOFF;

  #pragma unroll
  for (int nbl = 0; nbl < 4; ++nbl) {
    const int col = wn * 64 + nbl * 16 + c15;
    const int gcol = hw0 + col;
    float best = -1e30f; int bi = 0;
    #pragma unroll
    for (int mb = 0; mb < 2; ++mb) {
      #pragma unroll
      for (int r = 0; r < 4; ++r) {
        const int m = 32 * wm + mb * 16 + q * 4 + r;
        const size_t off = (bn + m) * HWDIM + gcol;
        const float v = cip[mb][nbl][r];
        ipo[off] = v;
        const float t = v + gumbel[off];
        if (t > best) { best = t; bi = m; }   // strict > keeps lowest m in-lane
      }
    }
    #pragma unroll
    for (int mk = 16; mk <= 32; mk <<= 1) {
      float ov = __shfl_xor(best, mk);
      int   oi = __shfl_xor(bi, mk);
      if (ov > best || (ov == best && oi < bi)) { best = ov; bi = oi; }
    }
    float mx = -1e30f;
    #pragma unroll
    for (int mb = 0; mb < 2; ++mb)
      #pragma unroll
      for (int r = 0; r < 4; ++r) mx = fmaxf(mx, cnp[mb][nbl][r]);
    #pragma unroll
    for (int mk = 16; mk <= 32; mk <<= 1) mx = fmaxf(mx, __shfl_xor(mx, mk));
    if (q == 0) {
      pvv[wm * 128 + col] = best;
      pvi[wm * 128 + col] = bi;
      pnm[wm * 128 + col] = mx;
    }
  }
  __syncthreads();

  if (tid < 128) {
    float v = pvv[tid]; int i = pvi[tid];
    float v2 = pvv[128 + tid]; int i2 = pvi[128 + tid];
    if (v2 > v || (v2 == v && i2 < i)) { v = v2; i = i2; }
    float h = s_sh[i];
    hbuf[tid] = h;
    out[(size_t)b * HWDIM + hw0 + tid] = h;
    m2[tid] = fmaxf(pnm[tid], pnm[128 + tid]);
  }
  __syncthreads();

  #pragma unroll
  for (int nbl = 0; nbl < 4; ++nbl) {
    const int col = wn * 64 + nbl * 16 + c15;
    const float mm = m2[col];
    float s = 0.f;
    #pragma unroll
    for (int mb = 0; mb < 2; ++mb)
      #pragma unroll
      for (int r = 0; r < 4; ++r) s += __expf(cnp[mb][nbl][r] - mm);
    s += __shfl_xor(s, 16);
    s += __shfl_xor(s, 32);
    if (q == 0) pns[wm * 128 + col] = s;
  }
  __syncthreads();

  if (tid < 128) {
    float S = pns[tid] + pns[128 + tid];
    cbuf[tid] = 1.0f / S;
  }
  __syncthreads();

  if (tid < 64) {
    float hs = hbuf[tid] + hbuf[tid + 64];
    float cs = cbuf[tid] + cbuf[tid + 64];
    #pragma unroll
    for (int o = 32; o > 0; o >>= 1) {
      hs += __shfl_down(hs, o);
      cs += __shfl_down(cs, o);
    }
    if (tid == 0) {
      ws[WS_PH + b * NTILES + tile] = hs;
      ws[WS_PC + b * NTILES + tile] = cs;
    }
  }
#undef LOADB
#undef WRITE_B
#undef PHASE
}

// ---------------------------------------------------------------------------
// Finish: logits + cluster_loss from per-block partials (deterministic order)
// ---------------------------------------------------------------------------
__global__ __launch_bounds__(256) void finish_kernel(
    const float* __restrict__ ws, float* __restrict__ out) {
  __shared__ double sred[256];
  const int tid = threadIdx.x;
  {
    int bb = tid >> 4, lane = tid & 15;
    double s = 0.0;
    for (int t = lane; t < NTILES; t += 16) s += (double)ws[WS_PH + bb * NTILES + t];
    #pragma unroll
    for (int o = 8; o > 0; o >>= 1) s += __shfl_down(s, o, 16);
    if (lane == 0) out[LOGOFF + bb] = (float)(s / (double)HWDIM);
  }
  double c = 0.0;
  for (int i = tid; i < BATCH * NTILES; i += 256) c += (double)ws[WS_PC + i];
  sred[tid] = c;
  __syncthreads();
  for (int st = 128; st > 0; st >>= 1) {
    if (tid < st) sred[tid] += sred[tid + st];
    __syncthreads();
  }
  if (tid == 0) out[LOSSOFF] = (float)(-sred[0] / (double)(BATCH * HWDIM));
}

// ---------------------------------------------------------------------------
extern "C" void kernel_launch(void* const* d_in, const int* in_sizes, int n_in,
                              void* d_out, int out_size, void* d_ws, size_t ws_size,
                              hipStream_t stream) {
  const float* x       = (const float*)d_in[0];
  const float* centers = (const float*)d_in[1];
  const float* Aadj    = (const float*)d_in[2];
  const float* gumbel  = (const float*)d_in[3];
  const float* W_bc    = (const float*)d_in[4];
  const float* b_bc    = (const float*)d_in[5];
  const float* W_gcn   = (const float*)d_in[6];
  const float* b_gcn   = (const float*)d_in[7];
  float* out = (float*)d_out;
  float* ws  = (float*)d_ws;

  hipLaunchKernelGGL(prep1_kernel, dim3(NCLS), dim3(256), 0, stream,
                     centers, Aadj, W_bc, b_bc, ws);
  hipLaunchKernelGGL(prep2_kernel, dim3(128), dim3(256), 0, stream,
                     W_gcn, b_gcn, ws);
  hipLaunchKernelGGL(pack_kernel, dim3(32), dim3(256), 0, stream, ws);
  hipLaunchKernelGGL(main_kernel, dim3(NTILES, BATCH), dim3(256), 0, stream,
                     x, gumbel, ws, out);
  hipLaunchKernelGGL(finish_kernel, dim3(1), dim3(256), 0, stream, ws, out);
}